// Round 1
// baseline (2074.851 us; speedup 1.0000x reference)
//
#include <hip/hip_runtime.h>

#define N_NODES 50000
#define N_EDGES 800000
#define DIM 128          // floats per node row
#define DIM4 (DIM / 4)   // float4 per node row

// ---------------- degree ----------------
__global__ void deg_count_kernel(const int* __restrict__ edge_dst,
                                 float* __restrict__ deg) {
    int e = blockIdx.x * blockDim.x + threadIdx.x;
    if (e < N_EDGES) {
        atomicAdd(&deg[edge_dst[e]], 1.0f);
    }
}

__global__ void inv_deg_kernel(float* __restrict__ deg) {
    int v = blockIdx.x * blockDim.x + threadIdx.x;
    if (v < N_NODES) {
        deg[v] = 1.0f / fmaxf(deg[v], 1.0f);
    }
}

// ---------------- init: tmp = h, res = h ----------------
__global__ void init_kernel(const float* __restrict__ h,
                            float* __restrict__ tmp,
                            float* __restrict__ res) {
    int i = blockIdx.x * blockDim.x + threadIdx.x;  // over N*D/4
    if (i < N_NODES * DIM4) {
        float4 v = reinterpret_cast<const float4*>(h)[i];
        reinterpret_cast<float4*>(tmp)[i] = v;
        reinterpret_cast<float4*>(res)[i] = v;
    }
}

// ---------------- scatter: agg[dst] += tmp[src] ----------------
// One 64-lane wave per edge; each lane moves a float2 (128 floats / 64 lanes).
__global__ void scatter_kernel(const int* __restrict__ edge_src,
                               const int* __restrict__ edge_dst,
                               const float* __restrict__ tmp,
                               float* __restrict__ agg) {
    int gid  = blockIdx.x * blockDim.x + threadIdx.x;
    int e    = gid >> 6;         // edge index
    int lane = gid & 63;         // lane within wave
    if (e >= N_EDGES) return;
    int s = edge_src[e];
    int d = edge_dst[e];
    const float2 v =
        reinterpret_cast<const float2*>(tmp + (size_t)s * DIM)[lane];
    float* drow = agg + (size_t)d * DIM + lane * 2;
    atomicAdd(drow + 0, v.x);
    atomicAdd(drow + 1, v.y);
}

// ---------------- combine: tmp += agg*invdeg; res += tmp*scale ----------------
__global__ void combine_kernel(const float* __restrict__ agg,
                               const float* __restrict__ inv_deg,
                               float* __restrict__ tmp,
                               float* __restrict__ res,
                               float scale) {
    int i = blockIdx.x * blockDim.x + threadIdx.x;  // over N*D/4
    if (i >= N_NODES * DIM4) return;
    int row = i >> 5;  // i / DIM4, DIM4 == 32
    float id = inv_deg[row];
    float4 a = reinterpret_cast<const float4*>(agg)[i];
    float4 t = reinterpret_cast<float4*>(tmp)[i];
    t.x += a.x * id;
    t.y += a.y * id;
    t.z += a.z * id;
    t.w += a.w * id;
    reinterpret_cast<float4*>(tmp)[i] = t;
    float4 r = reinterpret_cast<float4*>(res)[i];
    r.x += t.x * scale;
    r.y += t.y * scale;
    r.z += t.z * scale;
    r.w += t.w * scale;
    reinterpret_cast<float4*>(res)[i] = r;
}

extern "C" void kernel_launch(void* const* d_in, const int* in_sizes, int n_in,
                              void* d_out, int out_size, void* d_ws, size_t ws_size,
                              hipStream_t stream) {
    const float* h        = (const float*)d_in[0];
    const int*   edge_src = (const int*)d_in[1];
    const int*   edge_dst = (const int*)d_in[2];
    float*       res      = (float*)d_out;

    // Workspace layout (needs ~51.5 MB):
    //   deg/inv_deg : N floats               @ 0
    //   tmp         : N*D floats (25.6 MB)   @ 256 KiB
    //   agg         : N*D floats (25.6 MB)   @ 256 KiB + 25.6 MB
    char* ws = (char*)d_ws;
    float* deg = (float*)(ws);
    float* tmp = (float*)(ws + (256u << 10));
    float* agg = (float*)(ws + (256u << 10) + (size_t)N_NODES * DIM * sizeof(float));

    const int BLK = 256;
    const int nElem4 = N_NODES * DIM4;  // 1.6M float4 elements

    // degree
    hipMemsetAsync(deg, 0, N_NODES * sizeof(float), stream);
    deg_count_kernel<<<(N_EDGES + BLK - 1) / BLK, BLK, 0, stream>>>(edge_dst, deg);
    inv_deg_kernel<<<(N_NODES + BLK - 1) / BLK, BLK, 0, stream>>>(deg);

    // init
    init_kernel<<<(nElem4 + BLK - 1) / BLK, BLK, 0, stream>>>(h, tmp, res);

    // 3 SAGE-mean layers
    for (int layer = 0; layer < 3; ++layer) {
        hipMemsetAsync(agg, 0, (size_t)N_NODES * DIM * sizeof(float), stream);
        // 64 threads per edge
        long long threads = (long long)N_EDGES * 64;
        scatter_kernel<<<(int)((threads + BLK - 1) / BLK), BLK, 0, stream>>>(
            edge_src, edge_dst, tmp, agg);
        float scale = 1.0f / (1.0f + (float)layer);
        combine_kernel<<<(nElem4 + BLK - 1) / BLK, BLK, 0, stream>>>(
            agg, deg, tmp, res, scale);
    }
}

// Round 2
// 258.081 us; speedup vs baseline: 8.0395x; 8.0395x over previous
//
#include <hip/hip_runtime.h>

#define N_NODES 50000
#define N_EDGES 800000
#define DIM 128
#define SCAN_BLOCKS 196  // ceil(50000/256)

// ---------------- degree histogram (int atomics) ----------------
__global__ void hist_kernel(const int* __restrict__ edge_dst,
                            int* __restrict__ deg) {
    int e = blockIdx.x * blockDim.x + threadIdx.x;
    if (e < N_EDGES) atomicAdd(&deg[edge_dst[e]], 1);
}

// ---------------- scan step 1: per-block exclusive scan ----------------
__global__ void scan1_kernel(const int* __restrict__ deg,
                             int* __restrict__ row_start,
                             int* __restrict__ partials) {
    __shared__ int sm[256];
    int tid = threadIdx.x;
    int i = blockIdx.x * 256 + tid;
    int v = (i < N_NODES) ? deg[i] : 0;
    sm[tid] = v;
    __syncthreads();
    int x = v;
    for (int off = 1; off < 256; off <<= 1) {
        int y = (tid >= off) ? sm[tid - off] : 0;
        __syncthreads();
        x += y;
        sm[tid] = x;
        __syncthreads();
    }
    if (i < N_NODES) row_start[i] = x - v;  // exclusive
    if (tid == 255) partials[blockIdx.x] = x;  // block total
}

// ---------------- scan step 2: scan the block totals (1 block) ----------------
__global__ void scan2_kernel(int* __restrict__ partials) {
    __shared__ int sm[256];
    int tid = threadIdx.x;
    int v = (tid < SCAN_BLOCKS) ? partials[tid] : 0;
    sm[tid] = v;
    __syncthreads();
    int x = v;
    for (int off = 1; off < 256; off <<= 1) {
        int y = (tid >= off) ? sm[tid - off] : 0;
        __syncthreads();
        x += y;
        sm[tid] = x;
        __syncthreads();
    }
    if (tid < SCAN_BLOCKS) partials[tid] = x - v;  // exclusive
}

// ---------------- scan step 3: add block offsets; init cursor ----------------
__global__ void scan3_kernel(int* __restrict__ row_start,
                             const int* __restrict__ partials,
                             int* __restrict__ cursor) {
    int i = blockIdx.x * blockDim.x + threadIdx.x;
    if (i < N_NODES) {
        int rs = row_start[i] + partials[i >> 8];
        row_start[i] = rs;
        cursor[i] = rs;  // cursor aliases deg buffer; deg no longer needed
    }
    if (i == 0) row_start[N_NODES] = N_EDGES;
}

// ---------------- place edges: counting-sort by dst ----------------
__global__ void place_kernel(const int* __restrict__ edge_src,
                             const int* __restrict__ edge_dst,
                             int* __restrict__ cursor,
                             unsigned short* __restrict__ sorted_src) {
    int e = blockIdx.x * blockDim.x + threadIdx.x;
    if (e < N_EDGES) {
        int d = edge_dst[e];
        int pos = atomicAdd(&cursor[d], 1);
        sorted_src[pos] = (unsigned short)edge_src[e];  // ids < 65536
    }
}

// ---------------- bf16x2 pack (RNE) ----------------
__device__ __forceinline__ unsigned int pack_bf16x2(float x, float y) {
    unsigned int bx = __float_as_uint(x);
    unsigned int by = __float_as_uint(y);
    bx = (bx + 0x7fffu + ((bx >> 16) & 1u)) >> 16;
    by = (by + 0x7fffu + ((by >> 16) & 1u)) & 0xffff0000u;
    return (bx & 0xffffu) | by;
}

// ---------------- fused layer: u_out = M*src ; res accumulate ----------------
// One 64-lane wave per node; each lane owns 2 columns (lane*2, lane*2+1).
// FIRST:  res = (17/6)*h + coeff*u      (h == src, f32)
// !FIRST: res += coeff*u
// STORE:  u_out[idx] = bf16x2(u)
template <bool FIRST, bool STORE, bool SRC_BF16>
__global__ void sage_layer_kernel(const unsigned short* __restrict__ sorted_src,
                                  const int* __restrict__ row_start,
                                  const void* __restrict__ srcv,
                                  const float* __restrict__ h,
                                  unsigned int* __restrict__ u_out,
                                  float* __restrict__ res,
                                  float coeff) {
    int gid = blockIdx.x * blockDim.x + threadIdx.x;
    int node = gid >> 6;
    int lane = gid & 63;
    if (node >= N_NODES) return;
    int start = row_start[node];
    int end = row_start[node + 1];

    float ax = 0.0f, ay = 0.0f;
    if (SRC_BF16) {
        const unsigned int* s32 = (const unsigned int*)srcv;
        int j = start;
        for (; j + 1 < end; j += 2) {
            int s0 = sorted_src[j];
            int s1 = sorted_src[j + 1];
            unsigned int v0 = s32[s0 * 64 + lane];
            unsigned int v1 = s32[s1 * 64 + lane];
            ax += __uint_as_float(v0 << 16);
            ay += __uint_as_float(v0 & 0xffff0000u);
            ax += __uint_as_float(v1 << 16);
            ay += __uint_as_float(v1 & 0xffff0000u);
        }
        if (j < end) {
            int s0 = sorted_src[j];
            unsigned int v0 = s32[s0 * 64 + lane];
            ax += __uint_as_float(v0 << 16);
            ay += __uint_as_float(v0 & 0xffff0000u);
        }
    } else {
        const float2* s2 = (const float2*)srcv;
        int j = start;
        for (; j + 1 < end; j += 2) {
            int s0 = sorted_src[j];
            int s1 = sorted_src[j + 1];
            float2 v0 = s2[s0 * 64 + lane];
            float2 v1 = s2[s1 * 64 + lane];
            ax += v0.x;
            ay += v0.y;
            ax += v1.x;
            ay += v1.y;
        }
        if (j < end) {
            int s0 = sorted_src[j];
            float2 v0 = s2[s0 * 64 + lane];
            ax += v0.x;
            ay += v0.y;
        }
    }

    float id = 1.0f / (float)max(end - start, 1);
    float ux = ax * id;
    float uy = ay * id;

    int idx = node * 64 + lane;
    if (STORE) u_out[idx] = pack_bf16x2(ux, uy);

    if (FIRST) {
        float2 hv = reinterpret_cast<const float2*>(h)[idx];
        float2 r;
        r.x = fmaf(2.8333333f, hv.x, coeff * ux);
        r.y = fmaf(2.8333333f, hv.y, coeff * uy);
        reinterpret_cast<float2*>(res)[idx] = r;
    } else {
        float2 r = reinterpret_cast<float2*>(res)[idx];
        r.x = fmaf(coeff, ux, r.x);
        r.y = fmaf(coeff, uy, r.y);
        reinterpret_cast<float2*>(res)[idx] = r;
    }
}

extern "C" void kernel_launch(void* const* d_in, const int* in_sizes, int n_in,
                              void* d_out, int out_size, void* d_ws, size_t ws_size,
                              hipStream_t stream) {
    const float* h        = (const float*)d_in[0];
    const int*   edge_src = (const int*)d_in[1];
    const int*   edge_dst = (const int*)d_in[2];
    float*       res      = (float*)d_out;

    // Workspace layout (~34 MB total):
    char* ws = (char*)d_ws;
    int* deg_cursor        = (int*)(ws);                        // N ints (reused as cursor)
    int* row_start         = (int*)(ws + 262144);               // N+1 ints
    int* partials          = (int*)(ws + 589824);               // 256 ints
    unsigned short* sorted = (unsigned short*)(ws + 655360);    // E u16 (1.6 MB)
    unsigned int* u1       = (unsigned int*)(ws + 4194304);     // N*64 u32 (12.8 MB)
    unsigned int* u2       = (unsigned int*)(ws + 20971520);    // N*64 u32 (12.8 MB)

    const int BLK = 256;

    // ---- CSR build ----
    hipMemsetAsync(deg_cursor, 0, N_NODES * sizeof(int), stream);
    hist_kernel<<<(N_EDGES + BLK - 1) / BLK, BLK, 0, stream>>>(edge_dst, deg_cursor);
    scan1_kernel<<<SCAN_BLOCKS, BLK, 0, stream>>>(deg_cursor, row_start, partials);
    scan2_kernel<<<1, BLK, 0, stream>>>(partials);
    scan3_kernel<<<SCAN_BLOCKS, BLK, 0, stream>>>(row_start, partials, deg_cursor);
    place_kernel<<<(N_EDGES + BLK - 1) / BLK, BLK, 0, stream>>>(
        edge_src, edge_dst, deg_cursor, sorted);

    // ---- 3 fused layers: res = (17/6)h + 3*Mh + 1.5*M^2 h + (1/3)*M^3 h ----
    const int LGRID = N_NODES / 4;  // 12500 blocks x 4 waves = 50000 waves
    sage_layer_kernel<true, true, false><<<LGRID, BLK, 0, stream>>>(
        sorted, row_start, (const void*)h, h, u1, res, 3.0f);
    sage_layer_kernel<false, true, true><<<LGRID, BLK, 0, stream>>>(
        sorted, row_start, (const void*)u1, nullptr, u2, res, 1.5f);
    sage_layer_kernel<false, false, true><<<LGRID, BLK, 0, stream>>>(
        sorted, row_start, (const void*)u2, nullptr, nullptr, res, 1.0f / 3.0f);
}

// Round 3
// 209.253 us; speedup vs baseline: 9.9155x; 1.2333x over previous
//
#include <hip/hip_runtime.h>

#define N_NODES 50000
#define N_EDGES 800000
#define DIM 128
#define SCAN_BLOCKS 196              // ceil(50000/256)
#define SENTINEL 50000               // zero-row index (u16-safe)
#define PAD_CAP (N_EDGES + 7 * N_NODES)  // 1,150,000 max padded slots

// ---------------- degree histogram (int atomics) ----------------
__global__ void hist_kernel(const int* __restrict__ edge_dst,
                            int* __restrict__ deg) {
    int e = blockIdx.x * blockDim.x + threadIdx.x;
    if (e < N_EDGES) atomicAdd(&deg[edge_dst[e]], 1);
}

// ---------------- scan step 1: per-block exclusive scan of PADDED deg ----------------
__global__ void scan1_kernel(const int* __restrict__ deg,
                             int* __restrict__ prs,
                             int* __restrict__ partials) {
    __shared__ int sm[256];
    int tid = threadIdx.x;
    int i = blockIdx.x * 256 + tid;
    int v = (i < N_NODES) ? ((deg[i] + 7) & ~7) : 0;   // pad to multiple of 8
    sm[tid] = v;
    __syncthreads();
    int x = v;
    for (int off = 1; off < 256; off <<= 1) {
        int y = (tid >= off) ? sm[tid - off] : 0;
        __syncthreads();
        x += y;
        sm[tid] = x;
        __syncthreads();
    }
    if (i < N_NODES) prs[i] = x - v;       // exclusive
    if (tid == 255) partials[blockIdx.x] = x;
}

// ---------------- scan step 2: scan block totals (1 block) ----------------
__global__ void scan2_kernel(int* __restrict__ partials) {
    __shared__ int sm[256];
    int tid = threadIdx.x;
    int v = (tid < SCAN_BLOCKS) ? partials[tid] : 0;
    sm[tid] = v;
    __syncthreads();
    int x = v;
    for (int off = 1; off < 256; off <<= 1) {
        int y = (tid >= off) ? sm[tid - off] : 0;
        __syncthreads();
        x += y;
        sm[tid] = x;
        __syncthreads();
    }
    if (tid < SCAN_BLOCKS) partials[tid] = x - v;
}

// ---------------- scan step 3: finalize prs, cursor, inv_deg ----------------
__global__ void scan3_kernel(int* __restrict__ prs,
                             const int* __restrict__ partials,
                             const int* __restrict__ deg,
                             int* __restrict__ cursor,
                             float* __restrict__ inv_deg) {
    int i = blockIdx.x * blockDim.x + threadIdx.x;
    if (i < N_NODES) {
        int rs = prs[i] + partials[i >> 8];
        prs[i] = rs;
        cursor[i] = rs;
        int d = deg[i];
        inv_deg[i] = 1.0f / (float)max(d, 1);
        if (i == N_NODES - 1) prs[N_NODES] = rs + ((d + 7) & ~7);
    }
}

// ---------------- fill sorted with sentinel ----------------
__global__ void fill_kernel(unsigned int* __restrict__ sorted32) {
    int i = blockIdx.x * blockDim.x + threadIdx.x;  // over PAD_CAP/2 u32
    if (i < PAD_CAP / 2) sorted32[i] = 0xC350C350u;  // 50000 | 50000<<16
}

// ---------------- place edges: counting-sort by dst ----------------
__global__ void place_kernel(const int* __restrict__ edge_src,
                             const int* __restrict__ edge_dst,
                             int* __restrict__ cursor,
                             unsigned short* __restrict__ sorted_src) {
    int e = blockIdx.x * blockDim.x + threadIdx.x;
    if (e < N_EDGES) {
        int d = edge_dst[e];
        int pos = atomicAdd(&cursor[d], 1);
        sorted_src[pos] = (unsigned short)edge_src[e];
    }
}

// ---------------- bf16x2 pack (RNE) ----------------
__device__ __forceinline__ unsigned int pack_bf16x2(float x, float y) {
    unsigned int bx = __float_as_uint(x);
    unsigned int by = __float_as_uint(y);
    bx = (bx + 0x7fffu + ((bx >> 16) & 1u)) >> 16;
    by = (by + 0x7fffu + ((by >> 16) & 1u)) & 0xffff0000u;
    return (bx & 0xffffu) | by;
}

// ---------------- convert h -> bf16x2, zero sentinel rows ----------------
__global__ void convert_kernel(const float* __restrict__ h,
                               unsigned int* __restrict__ hb,
                               unsigned int* __restrict__ u1) {
    int idx = blockIdx.x * blockDim.x + threadIdx.x;  // over (N+1)*64
    if (idx >= (N_NODES + 1) * 64) return;
    if ((idx >> 6) == N_NODES) {
        hb[idx] = 0u;
        u1[idx] = 0u;
    } else {
        float2 v = reinterpret_cast<const float2*>(h)[idx];
        hb[idx] = pack_bf16x2(v.x, v.y);
    }
}

// ---------------- fused layer (all-bf16 src) ----------------
// One wave per node. 4 groups x 16 lanes; group g handles edge j+g, lane sub
// reads uint4 = 8 bf16 cols [sub*8, sub*8+8). One gather instr = 4 edge-rows (1 KB).
template <bool FIRST, bool STORE>
__global__ void sage_layer_kernel(const unsigned short* __restrict__ sorted_src,
                                  const int* __restrict__ prs,
                                  const float* __restrict__ inv_deg,
                                  const unsigned int* __restrict__ src,
                                  const float* __restrict__ h,
                                  unsigned int* __restrict__ u_out,
                                  float* __restrict__ res,
                                  float coeff) {
    int gid = blockIdx.x * blockDim.x + threadIdx.x;
    int node = gid >> 6;
    int lane = gid & 63;
    if (node >= N_NODES) return;
    int g = lane >> 4;     // edge group 0..3
    int sub = lane & 15;   // 16 lanes cover one 256-B row

    int start = prs[node];
    int end = prs[node + 1];   // padded: (end-start) % 8 == 0

    float a0 = 0.f, a1 = 0.f, a2 = 0.f, a3 = 0.f;
    float a4 = 0.f, a5 = 0.f, a6 = 0.f, a7 = 0.f;

    const uint4* s4 = reinterpret_cast<const uint4*>(src);
    for (int j = start; j < end; j += 8) {
        int i0 = sorted_src[j + g];
        int i1 = sorted_src[j + 4 + g];
        uint4 v0 = s4[i0 * 16 + sub];
        uint4 v1 = s4[i1 * 16 + sub];
        a0 += __uint_as_float(v0.x << 16);
        a1 += __uint_as_float(v0.x & 0xffff0000u);
        a2 += __uint_as_float(v0.y << 16);
        a3 += __uint_as_float(v0.y & 0xffff0000u);
        a4 += __uint_as_float(v0.z << 16);
        a5 += __uint_as_float(v0.z & 0xffff0000u);
        a6 += __uint_as_float(v0.w << 16);
        a7 += __uint_as_float(v0.w & 0xffff0000u);
        a0 += __uint_as_float(v1.x << 16);
        a1 += __uint_as_float(v1.x & 0xffff0000u);
        a2 += __uint_as_float(v1.y << 16);
        a3 += __uint_as_float(v1.y & 0xffff0000u);
        a4 += __uint_as_float(v1.z << 16);
        a5 += __uint_as_float(v1.z & 0xffff0000u);
        a6 += __uint_as_float(v1.w << 16);
        a7 += __uint_as_float(v1.w & 0xffff0000u);
    }

    // reduce across the 4 groups (lane-xor 16 and 32)
    a0 += __shfl_xor(a0, 16); a0 += __shfl_xor(a0, 32);
    a1 += __shfl_xor(a1, 16); a1 += __shfl_xor(a1, 32);
    a2 += __shfl_xor(a2, 16); a2 += __shfl_xor(a2, 32);
    a3 += __shfl_xor(a3, 16); a3 += __shfl_xor(a3, 32);
    a4 += __shfl_xor(a4, 16); a4 += __shfl_xor(a4, 32);
    a5 += __shfl_xor(a5, 16); a5 += __shfl_xor(a5, 32);
    a6 += __shfl_xor(a6, 16); a6 += __shfl_xor(a6, 32);
    a7 += __shfl_xor(a7, 16); a7 += __shfl_xor(a7, 32);

    float inv = inv_deg[node];
    float u0 = a0 * inv, u1v = a1 * inv, u2v = a2 * inv, u3 = a3 * inv;
    float u4 = a4 * inv, u5 = a5 * inv, u6 = a6 * inv, u7 = a7 * inv;

    if (STORE && g >= 2) {
        // groups 2,3 write the bf16 u-row (256 B total)
        uint2 w;
        if (g == 2) w = make_uint2(pack_bf16x2(u0, u1v), pack_bf16x2(u2v, u3));
        else        w = make_uint2(pack_bf16x2(u4, u5), pack_bf16x2(u6, u7));
        reinterpret_cast<uint2*>(u_out + node * 64)[sub * 2 + (g - 2)] = w;
    }
    if (g < 2) {
        // groups 0,1 write the f32 res row (512 B total)
        int fi = node * 32 + sub * 2 + g;
        float4 uu = (g == 0) ? make_float4(u0, u1v, u2v, u3)
                             : make_float4(u4, u5, u6, u7);
        float4 r;
        if (FIRST) {
            float4 hv = reinterpret_cast<const float4*>(h)[fi];
            r.x = fmaf(2.8333333f, hv.x, coeff * uu.x);
            r.y = fmaf(2.8333333f, hv.y, coeff * uu.y);
            r.z = fmaf(2.8333333f, hv.z, coeff * uu.z);
            r.w = fmaf(2.8333333f, hv.w, coeff * uu.w);
        } else {
            r = reinterpret_cast<float4*>(res)[fi];
            r.x = fmaf(coeff, uu.x, r.x);
            r.y = fmaf(coeff, uu.y, r.y);
            r.z = fmaf(coeff, uu.z, r.z);
            r.w = fmaf(coeff, uu.w, r.w);
        }
        reinterpret_cast<float4*>(res)[fi] = r;
    }
}

extern "C" void kernel_launch(void* const* d_in, const int* in_sizes, int n_in,
                              void* d_out, int out_size, void* d_ws, size_t ws_size,
                              hipStream_t stream) {
    const float* h        = (const float*)d_in[0];
    const int*   edge_src = (const int*)d_in[1];
    const int*   edge_dst = (const int*)d_in[2];
    float*       res      = (float*)d_out;

    // Workspace layout (~30 MB):
    char* ws = (char*)d_ws;
    int* deg               = (int*)(ws);                      // N ints
    int* cursor            = (int*)(ws + 204800);             // N ints
    int* prs               = (int*)(ws + 409600);             // N+1 ints
    int* partials          = (int*)(ws + 614400);             // 256 ints
    float* inv_deg         = (float*)(ws + 617472);           // N floats
    unsigned short* sorted = (unsigned short*)(ws + 822272);  // PAD_CAP u16 (2.3 MB)
    unsigned int* hb       = (unsigned int*)(ws + 3222272);   // (N+1)*64 u32 (12.8 MB)
    unsigned int* u1       = (unsigned int*)(ws + 16039972 + 2204);  // align
    // recompute cleanly:
    hb = (unsigned int*)(ws + 4194304);                       // @ 4 MB
    u1 = (unsigned int*)(ws + 4194304 + 12816384);            // @ ~16.8 MB  ((N+1)*64*4 = 12,816,256 -> round 12,816,384)

    const int BLK = 256;

    // ---- CSR build (padded, dst-sorted) ----
    hipMemsetAsync(deg, 0, N_NODES * sizeof(int), stream);
    hist_kernel<<<(N_EDGES + BLK - 1) / BLK, BLK, 0, stream>>>(edge_dst, deg);
    scan1_kernel<<<SCAN_BLOCKS, BLK, 0, stream>>>(deg, prs, partials);
    scan2_kernel<<<1, BLK, 0, stream>>>(partials);
    scan3_kernel<<<SCAN_BLOCKS, BLK, 0, stream>>>(prs, partials, deg, cursor, inv_deg);
    fill_kernel<<<(PAD_CAP / 2 + BLK - 1) / BLK, BLK, 0, stream>>>(
        (unsigned int*)sorted);
    place_kernel<<<(N_EDGES + BLK - 1) / BLK, BLK, 0, stream>>>(
        edge_src, edge_dst, cursor, sorted);

    // ---- h -> bf16 (+ zero sentinel rows) ----
    convert_kernel<<<((N_NODES + 1) * 64 + BLK - 1) / BLK, BLK, 0, stream>>>(
        h, hb, u1);

    // ---- res = (17/6)h + 3*Mh + 1.5*M^2 h + (1/3)*M^3 h ----
    // u2 reuses hb's storage (hb dead after layer 1; sentinel row stays zero).
    unsigned int* u2 = hb;
    const int LGRID = (N_NODES * 64) / BLK;  // 12500 blocks
    sage_layer_kernel<true, true><<<LGRID, BLK, 0, stream>>>(
        sorted, prs, inv_deg, hb, h, u1, res, 3.0f);
    sage_layer_kernel<false, true><<<LGRID, BLK, 0, stream>>>(
        sorted, prs, inv_deg, u1, nullptr, u2, res, 1.5f);
    sage_layer_kernel<false, false><<<LGRID, BLK, 0, stream>>>(
        sorted, prs, inv_deg, u2, nullptr, nullptr, res, 1.0f / 3.0f);
}